// Round 1
// baseline (58868.658 us; speedup 1.0000x reference)
//
#include <hip/hip_runtime.h>
#include <math.h>

#define LSEQ 2432

__device__ __forceinline__ float gelu_f(float x){
  return 0.5f * x * (1.0f + erff(x * 0.70710678118654752440f));
}
__device__ __forceinline__ float sigmoid_f(float x){
  return 1.0f / (1.0f + __expf(-x));
}

// ---------- pi0: (B,1,2432,200) -> (B,25,2432,8), stride (1,25), padW 24, k=49
__global__ __launch_bounds__(256) void k_pi0(const float* __restrict__ x,
    const float* __restrict__ w, const float* __restrict__ bias,
    float* __restrict__ out){
  int idx = blockIdx.x * 256 + threadIdx.x;      // 19456 over (r,w)
  int o = blockIdx.y, b = blockIdx.z;
  int r = idx >> 3, wv = idx & 7;
  const float* xr = x + ((size_t)b * 2432 + r) * 200;
  const float* wt = w + o * 49;
  float acc = bias[o];
  int start = wv * 25 - 24;
  #pragma unroll
  for (int t = 0; t < 49; ++t){
    int ix = start + t;
    if (ix >= 0 && ix < 200) acc += xr[ix] * wt[t];
  }
  out[(((size_t)b * 25 + o) * 2432 + r) * 8 + wv] = acc;
}

// ---------- group norm (groups=5 over 25 ch) stats: 40 blocks
__global__ __launch_bounds__(256) void k_gn_reduce(const float* __restrict__ p, float* __restrict__ stats){
  int b = blockIdx.x / 5, g = blockIdx.x % 5;
  const float* base = p + ((size_t)b * 25 + g * 5) * 19456;
  float s = 0.f, s2 = 0.f;
  for (int i = threadIdx.x; i < 97280; i += 256){ float v = base[i]; s += v; s2 += v * v; }
  __shared__ float sh[256], sh2[256];
  int t = threadIdx.x;
  sh[t] = s; sh2[t] = s2; __syncthreads();
  for (int off = 128; off > 0; off >>= 1){
    if (t < off){ sh[t] += sh[t+off]; sh2[t] += sh2[t+off]; }
    __syncthreads();
  }
  if (t == 0){
    float m = sh[0] / 97280.f;
    float var = sh2[0] / 97280.f - m * m;
    stats[blockIdx.x * 2] = m;
    stats[blockIdx.x * 2 + 1] = rsqrtf(var + 1e-5f);
  }
}

__global__ __launch_bounds__(256) void k_gn_apply(float* __restrict__ p, const float* __restrict__ stats,
    const float* __restrict__ gw, const float* __restrict__ gb){
  size_t i = (size_t)blockIdx.x * 256 + threadIdx.x;   // 3,891,200
  int c = (int)((i / 19456) % 25);
  int b = (int)(i / 486400);
  int g = c / 5;
  float m = stats[(b*5+g)*2], istd = stats[(b*5+g)*2+1];
  float v = (p[i] - m) * istd * gw[c] + gb[c];
  p[i] = gelu_f(v);
}

// ---------- 25->25 conv k=3 along w (width 8, pad 1)
__global__ __launch_bounds__(256) void k_pconv3(const float* __restrict__ pin,
    const float* __restrict__ w, const float* __restrict__ bias, float* __restrict__ pout){
  int idx = blockIdx.x * 256 + threadIdx.x;
  int o = blockIdx.y, b = blockIdx.z;
  int r = idx >> 3, wv = idx & 7;
  const float* ib = pin + (size_t)b * 25 * 19456 + r * 8 + wv;
  const float* wo = w + o * 75;
  float acc = bias[o];
  #pragma unroll
  for (int i = 0; i < 25; ++i){
    const float* row = ib + (size_t)i * 19456;
    float w0 = wo[i*3], w1 = wo[i*3+1], w2 = wo[i*3+2];
    if (wv > 0) acc += row[-1] * w0;
    acc += row[0] * w1;
    if (wv < 7) acc += row[1] * w2;
  }
  pout[(((size_t)b*25 + o) * 2432 + r) * 8 + wv] = acc;
}

// ---------- pe[b,l,p] = p2[b, p>>3, l, p&7]
__global__ __launch_bounds__(256) void k_pe_build(const float* __restrict__ p2, float* __restrict__ pe){
  size_t i = (size_t)blockIdx.x * 256 + threadIdx.x;
  int p = (int)(i % 200);
  size_t rem = i / 200;
  int l = (int)(rem % 2432);
  int b = (int)(rem / 2432);
  pe[i] = p2[(((size_t)b*25 + (p>>3)) * 2432 + l) * 8 + (p & 7)];
}

// ---------- spec = |DFT_200(x)| / 200  (101 bins)
__global__ __launch_bounds__(256) void k_spec(const float* __restrict__ x, float* __restrict__ spec){
  __shared__ float xr[200], ct[200], st[200];
  int row = blockIdx.x;               // b*2432 + l
  int t = threadIdx.x;
  if (t < 200){
    xr[t] = x[(size_t)row * 200 + t];
    float ang = -0.031415926535897932385f * t;    // -2*pi/200 * t
    ct[t] = cosf(ang); st[t] = sinf(ang);
  }
  __syncthreads();
  if (t < 101){
    float re = 0.f, im = 0.f;
    int ph = 0;
    for (int k = 0; k < 200; ++k){
      re += xr[k] * ct[ph];
      im += xr[k] * st[ph];
      ph += t; if (ph >= 200) ph -= 200;
    }
    spec[(size_t)row * 101 + t] = sqrtf(re*re + im*im) * 0.005f;
  }
}

// ---------- pe += spec @ spec_w^T + spec_b
__global__ __launch_bounds__(256) void k_spec_mm(const float* __restrict__ spec,
    const float* __restrict__ sw, const float* __restrict__ sb, float* __restrict__ pe){
  __shared__ float sr[101];
  int row = blockIdx.x;
  int t = threadIdx.x;
  if (t < 101) sr[t] = spec[(size_t)row * 101 + t];
  __syncthreads();
  if (t < 200){
    const float* wr = sw + t * 101;
    float acc = sb[t];
    for (int f = 0; f < 101; ++f) acc += sr[f] * wr[f];
    pe[(size_t)row * 200 + t] += acc;
  }
}

// ---------- h[b,p,c*128+j] = pe[b,c,j,p] + depthwise19x7(pe^T)[b,p,c,j]
__global__ __launch_bounds__(128) void k_hbuild(const float* __restrict__ pe,
    const float* __restrict__ pw, const float* __restrict__ pb, float* __restrict__ h){
  int c = blockIdx.x;      // 19
  int p = blockIdx.y;      // 200
  int b = blockIdx.z;      // 8
  int j = threadIdx.x;     // 128
  const float* peb = pe + (size_t)b * 2432 * 200 + p;
  float conv = pb[p];
  const float* wp = pw + p * 133;
  for (int a = 0; a < 19; ++a){
    int hh = c - 9 + a;
    if (hh < 0 || hh >= 19) continue;
    const float* per = peb + (size_t)hh * 128 * 200;
    #pragma unroll
    for (int tt = 0; tt < 7; ++tt){
      int ww = j - 3 + tt;
      if (ww < 0 || ww >= 128) continue;
      conv += per[(size_t)ww * 200] * wp[a*7 + tt];
    }
  }
  float orig = peb[((size_t)c * 128 + j) * 200];
  h[((size_t)b * 200 + p) * 2432 + c * 128 + j] = orig + conv;
}

// ---------- generic GEMM: out[b,o,l] = fs*act(alpha*sum_k W[o*lda+k]X[b,k,l] + bias + res + acc)
__global__ __launch_bounds__(256) void k_gemm(const float* __restrict__ W,
    const float* __restrict__ X, const float* __restrict__ bias,
    const float* __restrict__ res, float* __restrict__ out,
    int O, int K, int lda, float alpha, float fs, int act, int accf){
  __shared__ float Ws[8][68];
  __shared__ float Xs[8][64];
  int l0 = blockIdx.x * 64, o0 = blockIdx.y * 64, b = blockIdx.z;
  int tid = threadIdx.x;
  int tx = tid & 15, ty = tid >> 4;
  float acc[4][4] = {};
  const float* Xb = X + (size_t)b * K * LSEQ;
  for (int k0 = 0; k0 < K; k0 += 8){
    {
      int e = tid;
      #pragma unroll
      for (int r = 0; r < 2; ++r, e += 256){
        int oo = e >> 3, kk = e & 7;
        int o = o0 + oo, k = k0 + kk;
        Ws[kk][oo] = (o < O && k < K) ? W[(size_t)o * lda + k] : 0.f;
      }
      e = tid;
      #pragma unroll
      for (int r = 0; r < 2; ++r, e += 256){
        int kk = e >> 6, ll = e & 63;
        int k = k0 + kk;
        Xs[kk][ll] = (k < K) ? Xb[(size_t)k * LSEQ + l0 + ll] : 0.f;
      }
    }
    __syncthreads();
    #pragma unroll
    for (int kk = 0; kk < 8; ++kk){
      float4 wv = *(const float4*)&Ws[kk][ty * 4];
      float4 xv = *(const float4*)&Xs[kk][tx * 4];
      float wa[4] = {wv.x, wv.y, wv.z, wv.w};
      float xa[4] = {xv.x, xv.y, xv.z, xv.w};
      #pragma unroll
      for (int i = 0; i < 4; ++i)
        #pragma unroll
        for (int jj = 0; jj < 4; ++jj)
          acc[i][jj] += wa[i] * xa[jj];
    }
    __syncthreads();
  }
  #pragma unroll
  for (int i = 0; i < 4; ++i){
    int o = o0 + ty * 4 + i;
    if (o >= O) continue;
    #pragma unroll
    for (int jj = 0; jj < 4; ++jj){
      int l = l0 + tx * 4 + jj;
      size_t oi = ((size_t)b * O + o) * LSEQ + l;
      float v = alpha * acc[i][jj];
      if (bias) v += bias[o];
      if (res) v += res[oi];
      if (accf) v += out[oi];
      if (act == 1) v = fmaxf(v, 0.f);
      else if (act == 2) v = gelu_f(v);
      out[oi] = v * fs;
    }
  }
}

// ---------- conv3: u = gelu(conv1d(hx+noise, cw(512,256,3), cb, pad1))
__global__ __launch_bounds__(256) void k_conv3(const float* __restrict__ W,
    const float* __restrict__ bias, const float* __restrict__ A,
    const float* __restrict__ Bb, float* __restrict__ U){
  __shared__ float Ws[8][3][68];
  __shared__ float Xs[8][68];
  int l0 = blockIdx.x * 64, o0 = blockIdx.y * 64, b = blockIdx.z;
  int tid = threadIdx.x;
  int tx = tid & 15, ty = tid >> 4;
  float acc[4][4] = {};
  const float* Ab = A + (size_t)b * 256 * LSEQ;
  const float* Nb = Bb + (size_t)b * 256 * LSEQ;
  for (int k0 = 0; k0 < 256; k0 += 8){
    for (int e = tid; e < 1536; e += 256){
      int oo = e / 24, q = e % 24;
      int kk = q / 3, t = q % 3;
      Ws[kk][t][oo] = W[(size_t)(o0 + oo) * 768 + (k0 + kk) * 3 + t];
    }
    for (int e = tid; e < 528; e += 256){
      int kk = e / 66, mm = e % 66;
      int li = l0 - 1 + mm;
      float v = 0.f;
      if (li >= 0 && li < LSEQ){
        size_t ii = (size_t)(k0 + kk) * LSEQ + li;
        v = Ab[ii] + Nb[ii];
      }
      Xs[kk][mm] = v;
    }
    __syncthreads();
    #pragma unroll
    for (int kk = 0; kk < 8; ++kk){
      float x6[6];
      float4 xv = *(const float4*)&Xs[kk][tx * 4];
      x6[0]=xv.x; x6[1]=xv.y; x6[2]=xv.z; x6[3]=xv.w;
      x6[4]=Xs[kk][tx*4+4]; x6[5]=Xs[kk][tx*4+5];
      #pragma unroll
      for (int t = 0; t < 3; ++t){
        float4 wv = *(const float4*)&Ws[kk][t][ty * 4];
        float wa[4]={wv.x,wv.y,wv.z,wv.w};
        #pragma unroll
        for (int i = 0; i < 4; ++i)
          #pragma unroll
          for (int jj = 0; jj < 4; ++jj)
            acc[i][jj] += wa[i] * x6[jj + t];
      }
    }
    __syncthreads();
  }
  #pragma unroll
  for (int i = 0; i < 4; ++i){
    int o = o0 + ty * 4 + i;
    #pragma unroll
    for (int jj = 0; jj < 4; ++jj){
      int l = l0 + tx * 4 + jj;
      U[((size_t)b * 512 + o) * LSEQ + l] = gelu_f(acc[i][jj] + bias[o]);
    }
  }
}

// ---------- s4 causal long conv + D skip: y[b,h,l] = sum_{j<=l} k[h,j]u[b,h,l-j] + D[h]u[b,h,l]
// zero-padding of ush below index 0 implements the causal mask for free.
__global__ __launch_bounds__(64) void k_s4(const float* __restrict__ kw,
    const float* __restrict__ Dv, const float* __restrict__ u, float* __restrict__ y){
  __shared__ float ksh[256];
  __shared__ float ush[768];
  int l0 = blockIdx.x * 512;
  int hh = blockIdx.y, b = blockIdx.z;
  int t = threadIdx.x;
  const float* kr = kw + (size_t)hh * LSEQ;
  const float* ur = u + ((size_t)b * 512 + hh) * LSEQ;
  float acc[8] = {};
  int lb = t * 8;
  int jmax = l0 + 512; if (jmax > LSEQ) jmax = LSEQ;
  for (int j0 = 0; j0 < jmax; j0 += 256){
    #pragma unroll
    for (int r = 0; r < 4; ++r){
      int j = j0 + r * 64 + t;
      ksh[r * 64 + t] = (j < jmax) ? kr[j] : 0.f;
    }
    int base = l0 - j0 - 255;
    #pragma unroll
    for (int r = 0; r < 12; ++r){
      int e = r * 64 + t;
      int ui = base + e;
      ush[e] = (ui >= 0 && ui < LSEQ) ? ur[ui] : 0.f;
    }
    __syncthreads();
    for (int jj = 0; jj < 256; jj += 8){
      int s = lb + 255 - jj;
      float4 K0 = *(const float4*)&ksh[jj];
      float4 K1 = *(const float4*)&ksh[jj + 4];
      float4 U0 = *(const float4*)&ush[s - 7];
      float4 U1 = *(const float4*)&ush[s - 3];
      float4 U2 = *(const float4*)&ush[s + 1];
      float4 U3 = *(const float4*)&ush[s + 5];
      float km[8] = {K0.x,K0.y,K0.z,K0.w,K1.x,K1.y,K1.z,K1.w};
      float uv[16] = {U0.x,U0.y,U0.z,U0.w,U1.x,U1.y,U1.z,U1.w,
                      U2.x,U2.y,U2.z,U2.w,U3.x,U3.y,U3.z,U3.w};
      #pragma unroll
      for (int i = 0; i < 8; ++i)
        #pragma unroll
        for (int m = 0; m < 8; ++m)
          acc[i] += km[m] * uv[i - m + 7];
    }
    __syncthreads();
  }
  float dv = Dv[hh];
  #pragma unroll
  for (int i = 0; i < 8; ++i){
    int l = l0 + lb + i;
    if (l < LSEQ) y[((size_t)b * 512 + hh) * LSEQ + l] = acc[i] + dv * ur[l];
  }
}

// ---------- RMS norm over 256 channels
__global__ __launch_bounds__(256) void k_rms(const float* __restrict__ hx,
    const float* __restrict__ sn, float* __restrict__ hn){
  int idx = blockIdx.x * 256 + threadIdx.x;  // 19456 = b*l
  int b = idx / 2432, l = idx % 2432;
  const float* p = hx + (size_t)b * 256 * LSEQ + l;
  float s = 0.f;
  #pragma unroll 8
  for (int c = 0; c < 256; ++c){ float v = p[(size_t)c * LSEQ]; s += v * v; }
  float inv = 1.0f / (sqrtf(s * (1.0f/256.0f)) + 1e-8f);
  float* q = hn + (size_t)b * 256 * LSEQ + l;
  #pragma unroll 8
  for (int c = 0; c < 256; ++c) q[(size_t)c * LSEQ] = sn[c] * p[(size_t)c * LSEQ] * inv;
}

// ---------- GLU: ht[b,c,l] = yo[b,c,l]*sigmoid(yo[b,c+512,l])
__global__ __launch_bounds__(256) void k_glu(const float* __restrict__ yo, float* __restrict__ ht){
  size_t i = (size_t)blockIdx.x * 256 + threadIdx.x;  // 8*512*2432
  int l = (int)(i % LSEQ);
  size_t rem = i / LSEQ;
  int c = (int)(rem % 512);
  int b = (int)(rem / 512);
  size_t i1 = ((size_t)b * 1024 + c) * LSEQ + l;
  size_t i2 = ((size_t)b * 1024 + c + 512) * LSEQ + l;
  ht[i] = yo[i1] * sigmoid_f(yo[i2]);
}

// ---------- gate: out = tanh(g1)*sigmoid(g2), g = ht + a
__global__ __launch_bounds__(256) void k_gate(const float* __restrict__ ht,
    const float* __restrict__ a, float* __restrict__ out){
  size_t i = (size_t)blockIdx.x * 256 + threadIdx.x;  // 8*256*2432
  int l = (int)(i % LSEQ);
  size_t rem = i / LSEQ;
  int c = (int)(rem % 256);
  int b = (int)(rem / 256);
  size_t i1 = ((size_t)b * 512 + c) * LSEQ + l;
  size_t i2 = ((size_t)b * 512 + c + 256) * LSEQ + l;
  float g1 = ht[i1] + a[i1];
  float g2 = ht[i2] + a[i2];
  out[i] = tanhf(g1) * sigmoid_f(g2);
}

// ---------- final LayerNorm over last dim (200) with transpose
__global__ __launch_bounds__(256) void k_ln(const float* __restrict__ o2,
    const float* __restrict__ lw, const float* __restrict__ lb2, float* __restrict__ out){
  __shared__ float s1[256], s2[256];
  int row = blockIdx.x;                 // b*2432 + l
  int b = row / 2432, l = row % 2432;
  int t = threadIdx.x;
  float v = 0.f;
  if (t < 200) v = o2[((size_t)b * 200 + t) * LSEQ + l];
  s1[t] = v; s2[t] = v * v;
  __syncthreads();
  for (int off = 128; off > 0; off >>= 1){
    if (t < off){ s1[t] += s1[t + off]; s2[t] += s2[t + off]; }
    __syncthreads();
  }
  float m = s1[0] * 0.005f;
  float var = s2[0] * 0.005f - m * m;
  float istd = rsqrtf(var + 1e-5f);
  if (t < 200) out[(size_t)row * 200 + t] = (v - m) * istd * lw[t] + lb2[t];
}

extern "C" void kernel_launch(void* const* d_in, const int* in_sizes, int n_in,
                              void* d_out, int out_size, void* d_ws, size_t ws_size,
                              hipStream_t stream){
  const float* x     = (const float*)d_in[0];
  const float* pe_w  = (const float*)d_in[1];
  const float* pe_b  = (const float*)d_in[2];
  const float* pi0_w = (const float*)d_in[3];
  const float* pi0_b = (const float*)d_in[4];
  const float* gn0_w = (const float*)d_in[5];
  const float* gn0_b = (const float*)d_in[6];
  const float* pi1_w = (const float*)d_in[7];
  const float* pi1_b = (const float*)d_in[8];
  const float* gn1_w = (const float*)d_in[9];
  const float* gn1_b = (const float*)d_in[10];
  const float* pi2_w = (const float*)d_in[11];
  const float* pi2_b = (const float*)d_in[12];
  const float* gn2_w = (const float*)d_in[13];
  const float* gn2_b = (const float*)d_in[14];
  const float* spec_w= (const float*)d_in[15];
  const float* spec_b= (const float*)d_in[16];
  const float* ic_w  = (const float*)d_in[17];
  const float* ic_b  = (const float*)d_in[18];
  const float* blk_sn= (const float*)d_in[19];
  const float* blk_cw= (const float*)d_in[20];
  const float* blk_cb= (const float*)d_in[21];
  const float* blk_k = (const float*)d_in[22];
  const float* blk_D = (const float*)d_in[23];
  const float* blk_ow= (const float*)d_in[24];
  const float* blk_ob= (const float*)d_in[25];
  const float* blk_Wv= (const float*)d_in[26];
  const float* blk_bv= (const float*)d_in[27];
  const float* blk_Wo= (const float*)d_in[28];
  const float* blk_bo= (const float*)d_in[29];
  const float* blk_rw= (const float*)d_in[30];
  const float* blk_rb= (const float*)d_in[31];
  const float* blk_sw= (const float*)d_in[32];
  const float* blk_sb= (const float*)d_in[33];
  const float* fc_w  = (const float*)d_in[34];
  const float* fc_b  = (const float*)d_in[35];
  const float* zc_w  = (const float*)d_in[36];
  const float* zc_b  = (const float*)d_in[37];
  const float* ln_w  = (const float*)d_in[38];
  const float* ln_b  = (const float*)d_in[39];

  float* Wsp = (float*)d_ws;
  const size_t NLL = (size_t)8 * 256 * 2432;    // 4,980,736 floats
  float* noise = Wsp;
  float* hxb   = Wsp + NLL;
  float* skb   = Wsp + 2 * NLL;
  float* hnb   = Wsp + 3 * NLL;
  float* outb  = Wsp + 4 * NLL;
  float* ub    = Wsp + 5 * NLL;       // 2*NLL
  float* ysb   = Wsp + 7 * NLL;       // 2*NLL
  float* yob   = Wsp + 9 * NLL;       // 4*NLL  -> total 13*NLL floats (~259 MB)

  // front-end aliases (dead before residual loop uses these regions)
  float* p0 = ub;
  float* p1 = ysb;
  float* p2 = ub;
  float* pe = yob;
  float* spec = yob + 3891200;
  float* hb = yob + 3891200 + 1964544;
  float* gnstats = outb;   // 80 floats

  const float SQ05 = 0.70710678118654752440f;   // sqrt(0.5)
  const float SQ16 = 0.40824829046386301637f;   // sqrt(1/6)

  // ---- PatchEmbedding ----
  k_pi0<<<dim3(76,25,8), 256, 0, stream>>>(x, pi0_w, pi0_b, p0);
  k_gn_reduce<<<40,256,0,stream>>>(p0, gnstats);
  k_gn_apply<<<15200,256,0,stream>>>(p0, gnstats, gn0_w, gn0_b);
  k_pconv3<<<dim3(76,25,8),256,0,stream>>>(p0, pi1_w, pi1_b, p1);
  k_gn_reduce<<<40,256,0,stream>>>(p1, gnstats);
  k_gn_apply<<<15200,256,0,stream>>>(p1, gnstats, gn1_w, gn1_b);
  k_pconv3<<<dim3(76,25,8),256,0,stream>>>(p1, pi2_w, pi2_b, p2);
  k_gn_reduce<<<40,256,0,stream>>>(p2, gnstats);
  k_gn_apply<<<15200,256,0,stream>>>(p2, gnstats, gn2_w, gn2_b);
  k_pe_build<<<15200,256,0,stream>>>(p2, pe);
  k_spec<<<19456,256,0,stream>>>(x, spec);
  k_spec_mm<<<19456,256,0,stream>>>(spec, spec_w, spec_b, pe);
  k_hbuild<<<dim3(19,200,8),128,0,stream>>>(pe, pe_w, pe_b, hb);
  k_gemm<<<dim3(38,4,8),256,0,stream>>>(ic_w, hb, ic_b, nullptr, noise, 256, 200, 200, 1.f, 1.f, 1, 0);
  hipMemcpyAsync(hxb, noise, NLL * sizeof(float), hipMemcpyDeviceToDevice, stream);

  // ---- residual blocks ----
  for (int i = 0; i < 6; ++i){
    const float* sn = blk_sn + i * 256;
    const float* cw = blk_cw + (size_t)i * 512 * 768;
    const float* cb = blk_cb + i * 512;
    const float* ow = blk_ow + (size_t)i * 1024 * 2048;
    const float* ob = blk_ob + i * 1024;
    const float* Wv = blk_Wv + (size_t)i * 512 * 512;
    const float* bv = blk_bv + i * 512;
    const float* Wo = blk_Wo + (size_t)i * 512 * 512;
    const float* bo = blk_bo + i * 512;
    const float* rw = blk_rw + (size_t)i * 256 * 256;
    const float* rb = blk_rb + i * 256;
    const float* sw = blk_sw + (size_t)i * 256 * 256;
    const float* sb = blk_sb + i * 256;

    k_rms<<<76,256,0,stream>>>(hxb, sn, hnb);
    k_conv3<<<dim3(38,8,8),256,0,stream>>>(cw, cb, hxb, noise, ub);
    for (int s = 0; s < 4; ++s){
      const float* kw = blk_k + ((size_t)i * 4 + s) * 512 * 2432;
      const float* Dv = blk_D + ((size_t)i * 4 + s) * 512;
      k_s4<<<dim3(5,512,8),64,0,stream>>>(kw, Dv, ub, ysb);
      k_gemm<<<dim3(38,16,8),256,0,stream>>>(ow + s * 512, ysb, s==0?ob:nullptr, nullptr, yob,
                                             1024, 512, 2048, 1.f, 1.f, 0, s==0?0:1);
    }
    k_glu<<<38912,256,0,stream>>>(yob, ysb);
    k_gemm<<<dim3(38,8,8),256,0,stream>>>(Wv, ysb, bv, nullptr, ub, 512, 512, 512, 1.f, 1.f, 0, 0);
    k_gemm<<<dim3(38,8,8),256,0,stream>>>(Wo, ub, bo, nullptr, yob, 512, 512, 512, 1.f, 1.f, 0, 0);
    k_gate<<<19456,256,0,stream>>>(ysb, yob, outb);
    k_gemm<<<dim3(38,4,8),256,0,stream>>>(rw, outb, rb, hnb, hxb, 256, 256, 256, 1.f, SQ05, 0, 0);
    k_gemm<<<dim3(38,4,8),256,0,stream>>>(sw, outb, sb, nullptr, skb, 256, 256, 256, 1.f, 1.f, 0, i==0?0:1);
  }

  // ---- tail ----
  k_gemm<<<dim3(38,4,8),256,0,stream>>>(fc_w, skb, fc_b, nullptr, hnb, 256, 256, 256, SQ16, 1.f, 1, 0);
  k_gemm<<<dim3(38,4,8),256,0,stream>>>(zc_w, hnb, zc_b, nullptr, ub, 200, 256, 256, 1.f, 1.f, 0, 0);
  k_ln<<<19456,256,0,stream>>>(ub, ln_w, ln_b, (float*)d_out);
}

// Round 2
// 27704.926 us; speedup vs baseline: 2.1248x; 2.1248x over previous
//
#include <hip/hip_runtime.h>
#include <math.h>

#define LSEQ 2432

__device__ __forceinline__ float gelu_f(float x){
  return 0.5f * x * (1.0f + erff(x * 0.70710678118654752440f));
}
__device__ __forceinline__ float sigmoid_f(float x){
  return 1.0f / (1.0f + __expf(-x));
}

// ---------- pi0: (B,1,2432,200) -> (B,25,2432,8), stride (1,25), padW 24, k=49
__global__ __launch_bounds__(256) void k_pi0(const float* __restrict__ x,
    const float* __restrict__ w, const float* __restrict__ bias,
    float* __restrict__ out){
  int idx = blockIdx.x * 256 + threadIdx.x;      // 19456 over (r,w)
  int o = blockIdx.y, b = blockIdx.z;
  int r = idx >> 3, wv = idx & 7;
  const float* xr = x + ((size_t)b * 2432 + r) * 200;
  const float* wt = w + o * 49;
  float acc = bias[o];
  int start = wv * 25 - 24;
  #pragma unroll
  for (int t = 0; t < 49; ++t){
    int ix = start + t;
    if (ix >= 0 && ix < 200) acc += xr[ix] * wt[t];
  }
  out[(((size_t)b * 25 + o) * 2432 + r) * 8 + wv] = acc;
}

// ---------- group norm (groups=5 over 25 ch) stats: 40 blocks
__global__ __launch_bounds__(256) void k_gn_reduce(const float* __restrict__ p, float* __restrict__ stats){
  int b = blockIdx.x / 5, g = blockIdx.x % 5;
  const float* base = p + ((size_t)b * 25 + g * 5) * 19456;
  float s = 0.f, s2 = 0.f;
  for (int i = threadIdx.x; i < 97280; i += 256){ float v = base[i]; s += v; s2 += v * v; }
  __shared__ float sh[256], sh2[256];
  int t = threadIdx.x;
  sh[t] = s; sh2[t] = s2; __syncthreads();
  for (int off = 128; off > 0; off >>= 1){
    if (t < off){ sh[t] += sh[t+off]; sh2[t] += sh2[t+off]; }
    __syncthreads();
  }
  if (t == 0){
    float m = sh[0] / 97280.f;
    float var = sh2[0] / 97280.f - m * m;
    stats[blockIdx.x * 2] = m;
    stats[blockIdx.x * 2 + 1] = rsqrtf(var + 1e-5f);
  }
}

__global__ __launch_bounds__(256) void k_gn_apply(float* __restrict__ p, const float* __restrict__ stats,
    const float* __restrict__ gw, const float* __restrict__ gb){
  size_t i = (size_t)blockIdx.x * 256 + threadIdx.x;   // 3,891,200
  int c = (int)((i / 19456) % 25);
  int b = (int)(i / 486400);
  int g = c / 5;
  float m = stats[(b*5+g)*2], istd = stats[(b*5+g)*2+1];
  float v = (p[i] - m) * istd * gw[c] + gb[c];
  p[i] = gelu_f(v);
}

// ---------- 25->25 conv k=3 along w (width 8, pad 1)
__global__ __launch_bounds__(256) void k_pconv3(const float* __restrict__ pin,
    const float* __restrict__ w, const float* __restrict__ bias, float* __restrict__ pout){
  int idx = blockIdx.x * 256 + threadIdx.x;
  int o = blockIdx.y, b = blockIdx.z;
  int r = idx >> 3, wv = idx & 7;
  const float* ib = pin + (size_t)b * 25 * 19456 + r * 8 + wv;
  const float* wo = w + o * 75;
  float acc = bias[o];
  #pragma unroll
  for (int i = 0; i < 25; ++i){
    const float* row = ib + (size_t)i * 19456;
    float w0 = wo[i*3], w1 = wo[i*3+1], w2 = wo[i*3+2];
    if (wv > 0) acc += row[-1] * w0;
    acc += row[0] * w1;
    if (wv < 7) acc += row[1] * w2;
  }
  pout[(((size_t)b*25 + o) * 2432 + r) * 8 + wv] = acc;
}

// ---------- pe[b,l,p] = p2[b, p>>3, l, p&7]
__global__ __launch_bounds__(256) void k_pe_build(const float* __restrict__ p2, float* __restrict__ pe){
  size_t i = (size_t)blockIdx.x * 256 + threadIdx.x;
  int p = (int)(i % 200);
  size_t rem = i / 200;
  int l = (int)(rem % 2432);
  int b = (int)(rem / 2432);
  pe[i] = p2[(((size_t)b*25 + (p>>3)) * 2432 + l) * 8 + (p & 7)];
}

// ---------- spec = |DFT_200(x)| / 200  (101 bins)
__global__ __launch_bounds__(256) void k_spec(const float* __restrict__ x, float* __restrict__ spec){
  __shared__ float xr[200], ct[200], st[200];
  int row = blockIdx.x;               // b*2432 + l
  int t = threadIdx.x;
  if (t < 200){
    xr[t] = x[(size_t)row * 200 + t];
    float ang = -0.031415926535897932385f * t;    // -2*pi/200 * t
    ct[t] = cosf(ang); st[t] = sinf(ang);
  }
  __syncthreads();
  if (t < 101){
    float re = 0.f, im = 0.f;
    int ph = 0;
    for (int k = 0; k < 200; ++k){
      re += xr[k] * ct[ph];
      im += xr[k] * st[ph];
      ph += t; if (ph >= 200) ph -= 200;
    }
    spec[(size_t)row * 101 + t] = sqrtf(re*re + im*im) * 0.005f;
  }
}

// ---------- pe += spec @ spec_w^T + spec_b
__global__ __launch_bounds__(256) void k_spec_mm(const float* __restrict__ spec,
    const float* __restrict__ sw, const float* __restrict__ sb, float* __restrict__ pe){
  __shared__ float sr[101];
  int row = blockIdx.x;
  int t = threadIdx.x;
  if (t < 101) sr[t] = spec[(size_t)row * 101 + t];
  __syncthreads();
  if (t < 200){
    const float* wr = sw + t * 101;
    float acc = sb[t];
    for (int f = 0; f < 101; ++f) acc += sr[f] * wr[f];
    pe[(size_t)row * 200 + t] += acc;
  }
}

// ---------- h[b,p,c*128+j] = pe[b,c,j,p] + depthwise19x7(pe^T)[b,p,c,j]
__global__ __launch_bounds__(128) void k_hbuild(const float* __restrict__ pe,
    const float* __restrict__ pw, const float* __restrict__ pb, float* __restrict__ h){
  int c = blockIdx.x;      // 19
  int p = blockIdx.y;      // 200
  int b = blockIdx.z;      // 8
  int j = threadIdx.x;     // 128
  const float* peb = pe + (size_t)b * 2432 * 200 + p;
  float conv = pb[p];
  const float* wp = pw + p * 133;
  for (int a = 0; a < 19; ++a){
    int hh = c - 9 + a;
    if (hh < 0 || hh >= 19) continue;
    const float* per = peb + (size_t)hh * 128 * 200;
    #pragma unroll
    for (int tt = 0; tt < 7; ++tt){
      int ww = j - 3 + tt;
      if (ww < 0 || ww >= 128) continue;
      conv += per[(size_t)ww * 200] * wp[a*7 + tt];
    }
  }
  float orig = peb[((size_t)c * 128 + j) * 200];
  h[((size_t)b * 200 + p) * 2432 + c * 128 + j] = orig + conv;
}

// ---------- generic GEMM: out[b,o,l] = fs*act(alpha*sum_k W[o*lda+k]X[b,k,l] + bias + res + acc)
// 128(o) x 128(l) tile, 256 threads, 8x8 per thread (two 4-chunks per dim at
// lane-stride 4 floats -> 2 addrs/bank = conflict-free LDS reads).
__global__ __launch_bounds__(256) void k_gemm(const float* __restrict__ W,
    const float* __restrict__ X, const float* __restrict__ bias,
    const float* __restrict__ res, float* __restrict__ out,
    int O, int K, int lda, float alpha, float fs, int act, int accf){
  __shared__ __align__(16) float Ws[8][132];
  __shared__ __align__(16) float Xs[8][132];
  int l0 = blockIdx.x * 128, o0 = blockIdx.y * 128, b = blockIdx.z;
  int tid = threadIdx.x;
  int tx = tid & 15, ty = tid >> 4;
  float acc[8][8] = {};
  const float* Xb = X + (size_t)b * K * LSEQ;
  for (int k0 = 0; k0 < K; k0 += 8){
    {
      // stage X: kk = tid>>5 (0..7), ll = (tid&31)*4
      int kk = tid >> 5;
      int ll = (tid & 31) * 4;
      float4 v = *(const float4*)(Xb + (size_t)(k0 + kk) * LSEQ + l0 + ll);
      *(float4*)&Xs[kk][ll] = v;
      // stage W: row r = tid>>1 (0..127), kq = (tid&1)*4
      int r = tid >> 1, kq = (tid & 1) * 4;
      int o = o0 + r;
      float4 wv = make_float4(0.f, 0.f, 0.f, 0.f);
      if (o < O) wv = *(const float4*)(W + (size_t)o * lda + k0 + kq);
      Ws[kq][r] = wv.x; Ws[kq+1][r] = wv.y; Ws[kq+2][r] = wv.z; Ws[kq+3][r] = wv.w;
    }
    __syncthreads();
    #pragma unroll
    for (int kk = 0; kk < 8; ++kk){
      float xa[8], wa[8];
      *(float4*)&xa[0] = *(const float4*)&Xs[kk][tx * 4];
      *(float4*)&xa[4] = *(const float4*)&Xs[kk][tx * 4 + 64];
      *(float4*)&wa[0] = *(const float4*)&Ws[kk][ty * 4];
      *(float4*)&wa[4] = *(const float4*)&Ws[kk][ty * 4 + 64];
      #pragma unroll
      for (int i = 0; i < 8; ++i)
        #pragma unroll
        for (int jj = 0; jj < 8; ++jj)
          acc[i][jj] += wa[i] * xa[jj];
    }
    __syncthreads();
  }
  #pragma unroll
  for (int i = 0; i < 8; ++i){
    int o = o0 + ty * 4 + (i & 3) + (i >> 2) * 64;
    if (o >= O) continue;
    #pragma unroll
    for (int jj = 0; jj < 8; ++jj){
      int l = l0 + tx * 4 + (jj & 3) + (jj >> 2) * 64;
      size_t oi = ((size_t)b * O + o) * LSEQ + l;
      float v = alpha * acc[i][jj];
      if (bias) v += bias[o];
      if (res) v += res[oi];
      if (accf) v += out[oi];
      if (act == 1) v = fmaxf(v, 0.f);
      else if (act == 2) v = gelu_f(v);
      out[oi] = v * fs;
    }
  }
}

// ---------- conv3: u = gelu(conv1d(hx+noise, cw(512,256,3), cb, pad1))
__global__ __launch_bounds__(256) void k_conv3(const float* __restrict__ W,
    const float* __restrict__ bias, const float* __restrict__ A,
    const float* __restrict__ Bb, float* __restrict__ U){
  __shared__ float Ws[8][3][68];
  __shared__ float Xs[8][68];
  int l0 = blockIdx.x * 64, o0 = blockIdx.y * 64, b = blockIdx.z;
  int tid = threadIdx.x;
  int tx = tid & 15, ty = tid >> 4;
  float acc[4][4] = {};
  const float* Ab = A + (size_t)b * 256 * LSEQ;
  const float* Nb = Bb + (size_t)b * 256 * LSEQ;
  for (int k0 = 0; k0 < 256; k0 += 8){
    for (int e = tid; e < 1536; e += 256){
      int oo = e / 24, q = e % 24;
      int kk = q / 3, t = q % 3;
      Ws[kk][t][oo] = W[(size_t)(o0 + oo) * 768 + (k0 + kk) * 3 + t];
    }
    for (int e = tid; e < 528; e += 256){
      int kk = e / 66, mm = e % 66;
      int li = l0 - 1 + mm;
      float v = 0.f;
      if (li >= 0 && li < LSEQ){
        size_t ii = (size_t)(k0 + kk) * LSEQ + li;
        v = Ab[ii] + Nb[ii];
      }
      Xs[kk][mm] = v;
    }
    __syncthreads();
    #pragma unroll
    for (int kk = 0; kk < 8; ++kk){
      float x6[6];
      float4 xv = *(const float4*)&Xs[kk][tx * 4];
      x6[0]=xv.x; x6[1]=xv.y; x6[2]=xv.z; x6[3]=xv.w;
      x6[4]=Xs[kk][tx*4+4]; x6[5]=Xs[kk][tx*4+5];
      #pragma unroll
      for (int t = 0; t < 3; ++t){
        float4 wv = *(const float4*)&Ws[kk][t][ty * 4];
        float wa[4]={wv.x,wv.y,wv.z,wv.w};
        #pragma unroll
        for (int i = 0; i < 4; ++i)
          #pragma unroll
          for (int jj = 0; jj < 4; ++jj)
            acc[i][jj] += wa[i] * x6[jj + t];
      }
    }
    __syncthreads();
  }
  #pragma unroll
  for (int i = 0; i < 4; ++i){
    int o = o0 + ty * 4 + i;
    #pragma unroll
    for (int jj = 0; jj < 4; ++jj){
      int l = l0 + tx * 4 + jj;
      U[((size_t)b * 512 + o) * LSEQ + l] = gelu_f(acc[i][jj] + bias[o]);
    }
  }
}

// ---------- s4 causal long conv + D skip, conflict-free version.
// y[b,h,l] = sum_{j<=l} k[h,j] u[b,h,l-j] + D[h] u[b,h,l]
// LDS pad every 8 floats -> lane stride 9 -> no bank conflicts.
// k stored reversed so the inner loop slides the u-window ascending.
#define PHYS(e) ((e) + ((e) >> 3))
__global__ __launch_bounds__(64) void k_s4(const float* __restrict__ kw,
    const float* __restrict__ Dv, const float* __restrict__ u, float* __restrict__ y){
  __shared__ __align__(16) float ksh[256];   // reversed k tile
  __shared__ __align__(16) float ush[864];   // 768 logical, padded
  int l0 = blockIdx.x * 512;
  int hh = blockIdx.y, b = blockIdx.z;
  int t = threadIdx.x;
  const float* kr = kw + (size_t)hh * LSEQ;
  const float* ur = u + ((size_t)b * 512 + hh) * LSEQ;
  float acc[8] = {};
  int lb = t * 8;
  int jmax = l0 + 512; if (jmax > LSEQ) jmax = LSEQ;
  for (int j0 = 0; j0 < jmax; j0 += 256){
    // stage reversed k: ksh[e] = k[j0+255-e] (0 beyond jmax)
    #pragma unroll
    for (int r = 0; r < 4; ++r){
      int e = r * 64 + t;
      int j = j0 + 255 - e;
      ksh[e] = (j < jmax) ? kr[j] : 0.f;
    }
    // stage u window: u_log[e] = u[l0-j0-255+e], e in [0,768)
    int base = l0 - j0 - 255;
    #pragma unroll
    for (int r = 0; r < 12; ++r){
      int e = r * 64 + t;
      int ui = base + e;
      ush[PHYS(e)] = (ui >= 0 && ui < LSEQ) ? ur[ui] : 0.f;
    }
    __syncthreads();
    // acc[i] += sum_p ksh[p] * u_log[lb+p+i]
    float Wr[8];
    #pragma unroll
    for (int i = 0; i < 8; ++i) Wr[i] = ush[PHYS(lb + i)];
    for (int p = 0; p < 256; p += 16){
      float4 ka = *(const float4*)&ksh[p];
      float4 kb = *(const float4*)&ksh[p + 4];
      float4 kc = *(const float4*)&ksh[p + 8];
      float4 kd = *(const float4*)&ksh[p + 12];
      float N1[8], N2[8];
      #pragma unroll
      for (int i = 0; i < 8; ++i) N1[i] = ush[PHYS(lb + p + 8 + i)];
      float k8a[8] = {ka.x, ka.y, ka.z, ka.w, kb.x, kb.y, kb.z, kb.w};
      #pragma unroll
      for (int m = 0; m < 8; ++m)
        #pragma unroll
        for (int i = 0; i < 8; ++i)
          acc[i] += k8a[m] * ((i + m < 8) ? Wr[i + m] : N1[i + m - 8]);
      #pragma unroll
      for (int i = 0; i < 8; ++i) N2[i] = ush[PHYS(lb + p + 16 + i)];
      float k8b[8] = {kc.x, kc.y, kc.z, kc.w, kd.x, kd.y, kd.z, kd.w};
      #pragma unroll
      for (int m = 0; m < 8; ++m)
        #pragma unroll
        for (int i = 0; i < 8; ++i)
          acc[i] += k8b[m] * ((i + m < 8) ? N1[i + m] : N2[i + m - 8]);
      #pragma unroll
      for (int i = 0; i < 8; ++i) Wr[i] = N2[i];
    }
    __syncthreads();
  }
  float dv = Dv[hh];
  #pragma unroll
  for (int i = 0; i < 8; ++i){
    int l = l0 + lb + i;
    if (l < LSEQ) y[((size_t)b * 512 + hh) * LSEQ + l] = acc[i] + dv * ur[l];
  }
}

// ---------- RMS norm over 256 channels
__global__ __launch_bounds__(256) void k_rms(const float* __restrict__ hx,
    const float* __restrict__ sn, float* __restrict__ hn){
  int idx = blockIdx.x * 256 + threadIdx.x;  // 19456 = b*l
  int b = idx / 2432, l = idx % 2432;
  const float* p = hx + (size_t)b * 256 * LSEQ + l;
  float s = 0.f;
  #pragma unroll 8
  for (int c = 0; c < 256; ++c){ float v = p[(size_t)c * LSEQ]; s += v * v; }
  float inv = 1.0f / (sqrtf(s * (1.0f/256.0f)) + 1e-8f);
  float* q = hn + (size_t)b * 256 * LSEQ + l;
  #pragma unroll 8
  for (int c = 0; c < 256; ++c) q[(size_t)c * LSEQ] = sn[c] * p[(size_t)c * LSEQ] * inv;
}

// ---------- GLU: ht[b,c,l] = yo[b,c,l]*sigmoid(yo[b,c+512,l])
__global__ __launch_bounds__(256) void k_glu(const float* __restrict__ yo, float* __restrict__ ht){
  size_t i = (size_t)blockIdx.x * 256 + threadIdx.x;  // 8*512*2432
  int l = (int)(i % LSEQ);
  size_t rem = i / LSEQ;
  int c = (int)(rem % 512);
  int b = (int)(rem / 512);
  size_t i1 = ((size_t)b * 1024 + c) * LSEQ + l;
  size_t i2 = ((size_t)b * 1024 + c + 512) * LSEQ + l;
  ht[i] = yo[i1] * sigmoid_f(yo[i2]);
}

// ---------- gate: out = tanh(g1)*sigmoid(g2), g = ht + a
__global__ __launch_bounds__(256) void k_gate(const float* __restrict__ ht,
    const float* __restrict__ a, float* __restrict__ out){
  size_t i = (size_t)blockIdx.x * 256 + threadIdx.x;  // 8*256*2432
  int l = (int)(i % LSEQ);
  size_t rem = i / LSEQ;
  int c = (int)(rem % 256);
  int b = (int)(rem / 256);
  size_t i1 = ((size_t)b * 512 + c) * LSEQ + l;
  size_t i2 = ((size_t)b * 512 + c + 256) * LSEQ + l;
  float g1 = ht[i1] + a[i1];
  float g2 = ht[i2] + a[i2];
  out[i] = tanhf(g1) * sigmoid_f(g2);
}

// ---------- final LayerNorm over last dim (200) with transpose
__global__ __launch_bounds__(256) void k_ln(const float* __restrict__ o2,
    const float* __restrict__ lw, const float* __restrict__ lb2, float* __restrict__ out){
  __shared__ float s1[256], s2[256];
  int row = blockIdx.x;                 // b*2432 + l
  int b = row / 2432, l = row % 2432;
  int t = threadIdx.x;
  float v = 0.f;
  if (t < 200) v = o2[((size_t)b * 200 + t) * LSEQ + l];
  s1[t] = v; s2[t] = v * v;
  __syncthreads();
  for (int off = 128; off > 0; off >>= 1){
    if (t < off){ s1[t] += s1[t + off]; s2[t] += s2[t + off]; }
    __syncthreads();
  }
  float m = s1[0] * 0.005f;
  float var = s2[0] * 0.005f - m * m;
  float istd = rsqrtf(var + 1e-5f);
  if (t < 200) out[(size_t)row * 200 + t] = (v - m) * istd * lw[t] + lb2[t];
}

extern "C" void kernel_launch(void* const* d_in, const int* in_sizes, int n_in,
                              void* d_out, int out_size, void* d_ws, size_t ws_size,
                              hipStream_t stream){
  const float* x     = (const float*)d_in[0];
  const float* pe_w  = (const float*)d_in[1];
  const float* pe_b  = (const float*)d_in[2];
  const float* pi0_w = (const float*)d_in[3];
  const float* pi0_b = (const float*)d_in[4];
  const float* gn0_w = (const float*)d_in[5];
  const float* gn0_b = (const float*)d_in[6];
  const float* pi1_w = (const float*)d_in[7];
  const float* pi1_b = (const float*)d_in[8];
  const float* gn1_w = (const float*)d_in[9];
  const float* gn1_b = (const float*)d_in[10];
  const float* pi2_w = (const float*)d_in[11];
  const float* pi2_b = (const float*)d_in[12];
  const float* gn2_w = (const float*)d_in[13];
  const float* gn2_b = (const float*)d_in[14];
  const float* spec_w= (const float*)d_in[15];
  const float* spec_b= (const float*)d_in[16];
  const float* ic_w  = (const float*)d_in[17];
  const float* ic_b  = (const float*)d_in[18];
  const float* blk_sn= (const float*)d_in[19];
  const float* blk_cw= (const float*)d_in[20];
  const float* blk_cb= (const float*)d_in[21];
  const float* blk_k = (const float*)d_in[22];
  const float* blk_D = (const float*)d_in[23];
  const float* blk_ow= (const float*)d_in[24];
  const float* blk_ob= (const float*)d_in[25];
  const float* blk_Wv= (const float*)d_in[26];
  const float* blk_bv= (const float*)d_in[27];
  const float* blk_Wo= (const float*)d_in[28];
  const float* blk_bo= (const float*)d_in[29];
  const float* blk_rw= (const float*)d_in[30];
  const float* blk_rb= (const float*)d_in[31];
  const float* blk_sw= (const float*)d_in[32];
  const float* blk_sb= (const float*)d_in[33];
  const float* fc_w  = (const float*)d_in[34];
  const float* fc_b  = (const float*)d_in[35];
  const float* zc_w  = (const float*)d_in[36];
  const float* zc_b  = (const float*)d_in[37];
  const float* ln_w  = (const float*)d_in[38];
  const float* ln_b  = (const float*)d_in[39];

  float* Wsp = (float*)d_ws;
  const size_t NLL = (size_t)8 * 256 * 2432;    // 4,980,736 floats
  float* noise = Wsp;
  float* hxb   = Wsp + NLL;
  float* skb   = Wsp + 2 * NLL;
  float* hnb   = Wsp + 3 * NLL;
  float* outb  = Wsp + 4 * NLL;
  float* ub    = Wsp + 5 * NLL;       // 2*NLL
  float* ysb   = Wsp + 7 * NLL;       // 2*NLL
  float* yob   = Wsp + 9 * NLL;       // 4*NLL  -> total 13*NLL floats (~259 MB)

  // front-end aliases (dead before residual loop uses these regions)
  float* p0 = ub;
  float* p1 = ysb;
  float* p2 = ub;
  float* pe = yob;
  float* spec = yob + 3891200;
  float* hb = yob + 3891200 + 1964544;
  float* gnstats = outb;   // 80 floats

  const float SQ05 = 0.70710678118654752440f;   // sqrt(0.5)
  const float SQ16 = 0.40824829046386301637f;   // sqrt(1/6)

  // ---- PatchEmbedding ----
  k_pi0<<<dim3(76,25,8), 256, 0, stream>>>(x, pi0_w, pi0_b, p0);
  k_gn_reduce<<<40,256,0,stream>>>(p0, gnstats);
  k_gn_apply<<<15200,256,0,stream>>>(p0, gnstats, gn0_w, gn0_b);
  k_pconv3<<<dim3(76,25,8),256,0,stream>>>(p0, pi1_w, pi1_b, p1);
  k_gn_reduce<<<40,256,0,stream>>>(p1, gnstats);
  k_gn_apply<<<15200,256,0,stream>>>(p1, gnstats, gn1_w, gn1_b);
  k_pconv3<<<dim3(76,25,8),256,0,stream>>>(p1, pi2_w, pi2_b, p2);
  k_gn_reduce<<<40,256,0,stream>>>(p2, gnstats);
  k_gn_apply<<<15200,256,0,stream>>>(p2, gnstats, gn2_w, gn2_b);
  k_pe_build<<<15200,256,0,stream>>>(p2, pe);
  k_spec<<<19456,256,0,stream>>>(x, spec);
  k_spec_mm<<<19456,256,0,stream>>>(spec, spec_w, spec_b, pe);
  k_hbuild<<<dim3(19,200,8),128,0,stream>>>(pe, pe_w, pe_b, hb);
  k_gemm<<<dim3(19,2,8),256,0,stream>>>(ic_w, hb, ic_b, nullptr, noise, 256, 200, 200, 1.f, 1.f, 1, 0);
  hipMemcpyAsync(hxb, noise, NLL * sizeof(float), hipMemcpyDeviceToDevice, stream);

  // ---- residual blocks ----
  for (int i = 0; i < 6; ++i){
    const float* sn = blk_sn + i * 256;
    const float* cw = blk_cw + (size_t)i * 512 * 768;
    const float* cb = blk_cb + i * 512;
    const float* ow = blk_ow + (size_t)i * 1024 * 2048;
    const float* ob = blk_ob + i * 1024;
    const float* Wv = blk_Wv + (size_t)i * 512 * 512;
    const float* bv = blk_bv + i * 512;
    const float* Wo = blk_Wo + (size_t)i * 512 * 512;
    const float* bo = blk_bo + i * 512;
    const float* rw = blk_rw + (size_t)i * 256 * 256;
    const float* rb = blk_rb + i * 256;
    const float* sw = blk_sw + (size_t)i * 256 * 256;
    const float* sb = blk_sb + i * 256;

    k_rms<<<76,256,0,stream>>>(hxb, sn, hnb);
    k_conv3<<<dim3(38,8,8),256,0,stream>>>(cw, cb, hxb, noise, ub);
    for (int s = 0; s < 4; ++s){
      const float* kw = blk_k + ((size_t)i * 4 + s) * 512 * 2432;
      const float* Dv = blk_D + ((size_t)i * 4 + s) * 512;
      k_s4<<<dim3(5,512,8),64,0,stream>>>(kw, Dv, ub, ysb);
      k_gemm<<<dim3(19,8,8),256,0,stream>>>(ow + s * 512, ysb, s==0?ob:nullptr, nullptr, yob,
                                             1024, 512, 2048, 1.f, 1.f, 0, s==0?0:1);
    }
    k_glu<<<38912,256,0,stream>>>(yob, ysb);
    k_gemm<<<dim3(19,4,8),256,0,stream>>>(Wv, ysb, bv, nullptr, ub, 512, 512, 512, 1.f, 1.f, 0, 0);
    k_gemm<<<dim3(19,4,8),256,0,stream>>>(Wo, ub, bo, nullptr, yob, 512, 512, 512, 1.f, 1.f, 0, 0);
    k_gate<<<19456,256,0,stream>>>(ysb, yob, outb);
    k_gemm<<<dim3(19,2,8),256,0,stream>>>(rw, outb, rb, hnb, hxb, 256, 256, 256, 1.f, SQ05, 0, 0);
    k_gemm<<<dim3(19,2,8),256,0,stream>>>(sw, outb, sb, nullptr, skb, 256, 256, 256, 1.f, 1.f, 0, i==0?0:1);
  }

  // ---- tail ----
  k_gemm<<<dim3(19,2,8),256,0,stream>>>(fc_w, skb, fc_b, nullptr, hnb, 256, 256, 256, SQ16, 1.f, 1, 0);
  k_gemm<<<dim3(19,2,8),256,0,stream>>>(zc_w, hnb, zc_b, nullptr, ub, 200, 256, 256, 1.f, 1.f, 0, 0);
  k_ln<<<19456,256,0,stream>>>(ub, ln_w, ln_b, (float*)d_out);
}

// Round 4
// 19529.878 us; speedup vs baseline: 3.0143x; 1.4186x over previous
//
#include <hip/hip_runtime.h>
#include <hip/hip_bf16.h>
#include <math.h>

#define LSEQ 2432

typedef short bf16x8 __attribute__((ext_vector_type(8)));
typedef float f32x4 __attribute__((ext_vector_type(4)));

__device__ __forceinline__ float gelu_f(float x){
  return 0.5f * x * (1.0f + erff(x * 0.70710678118654752440f));
}
__device__ __forceinline__ float sigmoid_f(float x){
  return 1.0f / (1.0f + __expf(-x));
}
__device__ __forceinline__ unsigned short f2bf(float f){
  __hip_bfloat16 h = __float2bfloat16(f);   // RNE
  return *reinterpret_cast<unsigned short*>(&h);
}

// ---------- pi0: (B,1,2432,200) -> (B,25,2432,8), stride (1,25), padW 24, k=49
__global__ __launch_bounds__(256) void k_pi0(const float* __restrict__ x,
    const float* __restrict__ w, const float* __restrict__ bias,
    float* __restrict__ out){
  int idx = blockIdx.x * 256 + threadIdx.x;
  int o = blockIdx.y, b = blockIdx.z;
  int r = idx >> 3, wv = idx & 7;
  const float* xr = x + ((size_t)b * 2432 + r) * 200;
  const float* wt = w + o * 49;
  float acc = bias[o];
  int start = wv * 25 - 24;
  #pragma unroll
  for (int t = 0; t < 49; ++t){
    int ix = start + t;
    if (ix >= 0 && ix < 200) acc += xr[ix] * wt[t];
  }
  out[(((size_t)b * 25 + o) * 2432 + r) * 8 + wv] = acc;
}

// ---------- group norm (groups=5 over 25 ch)
__global__ __launch_bounds__(256) void k_gn_reduce(const float* __restrict__ p, float* __restrict__ stats){
  int b = blockIdx.x / 5, g = blockIdx.x % 5;
  const float* base = p + ((size_t)b * 25 + g * 5) * 19456;
  float s = 0.f, s2 = 0.f;
  for (int i = threadIdx.x; i < 97280; i += 256){ float v = base[i]; s += v; s2 += v * v; }
  __shared__ float sh[256], sh2[256];
  int t = threadIdx.x;
  sh[t] = s; sh2[t] = s2; __syncthreads();
  for (int off = 128; off > 0; off >>= 1){
    if (t < off){ sh[t] += sh[t+off]; sh2[t] += sh2[t+off]; }
    __syncthreads();
  }
  if (t == 0){
    float m = sh[0] / 97280.f;
    float var = sh2[0] / 97280.f - m * m;
    stats[blockIdx.x * 2] = m;
    stats[blockIdx.x * 2 + 1] = rsqrtf(var + 1e-5f);
  }
}

__global__ __launch_bounds__(256) void k_gn_apply(float* __restrict__ p, const float* __restrict__ stats,
    const float* __restrict__ gw, const float* __restrict__ gb){
  size_t i = (size_t)blockIdx.x * 256 + threadIdx.x;
  int c = (int)((i / 19456) % 25);
  int b = (int)(i / 486400);
  int g = c / 5;
  float m = stats[(b*5+g)*2], istd = stats[(b*5+g)*2+1];
  float v = (p[i] - m) * istd * gw[c] + gb[c];
  p[i] = gelu_f(v);
}

// ---------- 25->25 conv k=3 along w (width 8, pad 1)
__global__ __launch_bounds__(256) void k_pconv3(const float* __restrict__ pin,
    const float* __restrict__ w, const float* __restrict__ bias, float* __restrict__ pout){
  int idx = blockIdx.x * 256 + threadIdx.x;
  int o = blockIdx.y, b = blockIdx.z;
  int r = idx >> 3, wv = idx & 7;
  const float* ib = pin + (size_t)b * 25 * 19456 + r * 8 + wv;
  const float* wo = w + o * 75;
  float acc = bias[o];
  #pragma unroll
  for (int i = 0; i < 25; ++i){
    const float* row = ib + (size_t)i * 19456;
    float w0 = wo[i*3], w1 = wo[i*3+1], w2 = wo[i*3+2];
    if (wv > 0) acc += row[-1] * w0;
    acc += row[0] * w1;
    if (wv < 7) acc += row[1] * w2;
  }
  pout[(((size_t)b*25 + o) * 2432 + r) * 8 + wv] = acc;
}

// ---------- pe[b,l,p] = p2[b, p>>3, l, p&7]
__global__ __launch_bounds__(256) void k_pe_build(const float* __restrict__ p2, float* __restrict__ pe){
  size_t i = (size_t)blockIdx.x * 256 + threadIdx.x;
  int p = (int)(i % 200);
  size_t rem = i / 200;
  int l = (int)(rem % 2432);
  int b = (int)(rem / 2432);
  pe[i] = p2[(((size_t)b*25 + (p>>3)) * 2432 + l) * 8 + (p & 7)];
}

// ---------- spec = |DFT_200(x)| / 200  (101 bins)
__global__ __launch_bounds__(256) void k_spec(const float* __restrict__ x, float* __restrict__ spec){
  __shared__ float xr[200], ct[200], st[200];
  int row = blockIdx.x;
  int t = threadIdx.x;
  if (t < 200){
    xr[t] = x[(size_t)row * 200 + t];
    float ang = -0.031415926535897932385f * t;
    ct[t] = cosf(ang); st[t] = sinf(ang);
  }
  __syncthreads();
  if (t < 101){
    float re = 0.f, im = 0.f;
    int ph = 0;
    for (int k = 0; k < 200; ++k){
      re += xr[k] * ct[ph];
      im += xr[k] * st[ph];
      ph += t; if (ph >= 200) ph -= 200;
    }
    spec[(size_t)row * 101 + t] = sqrtf(re*re + im*im) * 0.005f;
  }
}

// ---------- pe += spec @ spec_w^T + spec_b
__global__ __launch_bounds__(256) void k_spec_mm(const float* __restrict__ spec,
    const float* __restrict__ sw, const float* __restrict__ sb, float* __restrict__ pe){
  __shared__ float sr[101];
  int row = blockIdx.x;
  int t = threadIdx.x;
  if (t < 101) sr[t] = spec[(size_t)row * 101 + t];
  __syncthreads();
  if (t < 200){
    const float* wr = sw + t * 101;
    float acc = sb[t];
    for (int f = 0; f < 101; ++f) acc += sr[f] * wr[f];
    pe[(size_t)row * 200 + t] += acc;
  }
}

// ---------- pe (b,L,200) -> peT (b,200,L), 32x32 LDS tiles
__global__ __launch_bounds__(256) void k_trp(const float* __restrict__ pe, float* __restrict__ peT){
  __shared__ float ts[32][33];
  int l0 = blockIdx.x * 32, c0 = blockIdx.y * 32, b = blockIdx.z;
  int t = threadIdx.x;
  int i = t >> 5, j = t & 31;
  #pragma unroll
  for (int pass = 0; pass < 4; ++pass){
    int ii = i + pass * 8;
    int c = c0 + j;
    ts[ii][j] = (c < 200) ? pe[((size_t)b * 2432 + l0 + ii) * 200 + c] : 0.f;
  }
  __syncthreads();
  #pragma unroll
  for (int pass = 0; pass < 4; ++pass){
    int ii = i + pass * 8;
    int c = c0 + ii;
    if (c < 200) peT[((size_t)b * 200 + c) * 2432 + l0 + j] = ts[j][ii];
  }
}

// ---------- hbuild: h[b,p,c*128+j] = peT[b,p,c*128+j] + depthwise19x7 conv
__global__ __launch_bounds__(128) void k_hbuild2(const float* __restrict__ peT,
    const float* __restrict__ pw, const float* __restrict__ pb, float* __restrict__ h){
  __shared__ float T[19][136];
  __shared__ float wsh[133];
  int c = blockIdx.x, p = blockIdx.y, b = blockIdx.z;
  int tid = threadIdx.x;
  const float* pr = peT + ((size_t)b * 200 + p) * 2432;
  for (int e = tid; e < 19 * 136; e += 128){
    int a = e / 136, m = e % 136;
    int hh = c - 9 + a, ww = m - 3;
    float v = 0.f;
    if (hh >= 0 && hh < 19 && ww >= 0 && ww < 128) v = pr[hh * 128 + ww];
    T[a][m] = v;
  }
  for (int e = tid; e < 133; e += 128) wsh[e] = pw[p * 133 + e];
  __syncthreads();
  int j = tid;
  float conv = pb[p];
  #pragma unroll
  for (int a = 0; a < 19; ++a){
    #pragma unroll
    for (int tt = 0; tt < 7; ++tt) conv += T[a][j + tt] * wsh[a * 7 + tt];
  }
  float orig = T[9][j + 3];
  h[((size_t)b * 200 + p) * 2432 + c * 128 + j] = orig + conv;
}

// ---------- weight cast f32 [O][Kin] -> bf16 [O][Kpad] (zero pad)
__global__ __launch_bounds__(256) void k_wcast(const float* __restrict__ src,
    unsigned short* __restrict__ dst, int O, int Kin, int Kpad){
  size_t i = (size_t)blockIdx.x * 256 + threadIdx.x;
  if (i >= (size_t)O * Kpad) return;
  int k = (int)(i % Kpad);
  int o = (int)(i / Kpad);
  dst[i] = (k < Kin) ? f2bf(src[(size_t)o * Kin + k]) : 0;
}

// ---------- ow cast with GLU row interleave: dst row ro <- src row (ro>>1)+(ro&1)*512
__global__ __launch_bounds__(256) void k_wcast_glu(const float* __restrict__ src,
    unsigned short* __restrict__ dst){
  size_t i = (size_t)blockIdx.x * 256 + threadIdx.x;
  if (i >= (size_t)6 * 1024 * 2048) return;
  int k = (int)(i % 2048);
  size_t rem = i / 2048;
  int ro = (int)(rem % 1024);
  int blk = (int)(rem / 1024);
  int j = (ro >> 1) + (ro & 1) * 512;
  dst[i] = f2bf(src[((size_t)blk * 1024 + j) * 2048 + k]);
}

// ---------- cast+transpose f32 [b][C][L] -> bf16 [b][L][Kpad] cols [cbase, cbase+C)
__global__ __launch_bounds__(256) void k_castT(const float* __restrict__ in,
    unsigned short* __restrict__ out, int C, int Kpad, int cbase){
  __shared__ float ts[32][33];
  int l0 = blockIdx.x * 32, c0 = blockIdx.y * 32, b = blockIdx.z;
  int t = threadIdx.x;
  int i = t >> 5, j = t & 31;
  #pragma unroll
  for (int pass = 0; pass < 4; ++pass){
    int ci = c0 + i + pass * 8;
    ts[i + pass * 8][j] = (ci < C) ? in[((size_t)b * C + ci) * LSEQ + l0 + j] : 0.f;
  }
  __syncthreads();
  #pragma unroll
  for (int pass = 0; pass < 4; ++pass){
    int li = l0 + i + pass * 8;
    out[((size_t)b * LSEQ + li) * Kpad + cbase + c0 + j] = f2bf(ts[j][i + pass * 8]);
  }
}

// ---------- gate fused with cast+transpose: actT[b][l][c] = bf16(tanh(g1)*sigmoid(g2))
__global__ __launch_bounds__(256) void k_gateT(const float* __restrict__ ht,
    const float* __restrict__ a, unsigned short* __restrict__ out){
  __shared__ float ts[32][33];
  int l0 = blockIdx.x * 32, c0 = blockIdx.y * 32, b = blockIdx.z;
  int t = threadIdx.x;
  int i = t >> 5, j = t & 31;
  #pragma unroll
  for (int pass = 0; pass < 4; ++pass){
    int ci = c0 + i + pass * 8;
    size_t i1 = ((size_t)b * 512 + ci) * LSEQ + l0 + j;
    size_t i2 = ((size_t)b * 512 + ci + 256) * LSEQ + l0 + j;
    float g1 = ht[i1] + a[i1];
    float g2 = ht[i2] + a[i2];
    ts[i + pass * 8][j] = tanhf(g1) * sigmoid_f(g2);
  }
  __syncthreads();
  #pragma unroll
  for (int pass = 0; pass < 4; ++pass){
    int li = l0 + i + pass * 8;
    out[((size_t)b * LSEQ + li) * 256 + c0 + j] = f2bf(ts[j][i + pass * 8]);
  }
}

// ---------- rms inverse scale per (b,l)
__global__ __launch_bounds__(256) void k_rmsr(const float* __restrict__ hx, float* __restrict__ rinv){
  int idx = blockIdx.x * 256 + threadIdx.x;   // 19456
  int b = idx / 2432, l = idx % 2432;
  const float* p = hx + (size_t)b * 256 * LSEQ + l;
  float s = 0.f;
  #pragma unroll 8
  for (int c = 0; c < 256; ++c){ float v = p[(size_t)c * LSEQ]; s += v * v; }
  rinv[idx] = 1.0f / (sqrtf(s * (1.0f/256.0f)) + 1e-8f);
}

// ---------- bf16 MFMA GEMM.
// act: 0 none, 1 relu, 3 GLU(pair rows -> out has O/2=512 rows)
// res2 mode (sn!=nullptr): v += sn[o]*res[oi]*rinv[b*2432+l]
__global__ __launch_bounds__(256) void k_bgemm(const unsigned short* __restrict__ Wb,
    const unsigned short* __restrict__ Xb, const float* __restrict__ bias,
    const float* __restrict__ res, const float* __restrict__ sn,
    const float* __restrict__ rinv, float* __restrict__ out,
    int O, int Kpad, float alpha, float fs, int act, int accf){
  __shared__ unsigned short Ws[128 * 40];
  __shared__ unsigned short Xs[128 * 40];
  int l0 = blockIdx.x * 128, o0 = blockIdx.y * 128, b = blockIdx.z;
  int tid = threadIdx.x;
  int w = tid >> 6, lane = tid & 63;
  int ow_ = (w & 1) * 64, lw_ = (w >> 1) * 64;
  int m = lane & 15, q = (lane >> 4) & 3;
  const unsigned short* Xbb = Xb + (size_t)b * 2432 * Kpad;
  f32x4 acc[4][4] = {};
  for (int k0 = 0; k0 < Kpad; k0 += 32){
    #pragma unroll
    for (int r = 0; r < 2; ++r){
      int idx = tid + r * 256;
      int row = idx >> 2, cq = (idx & 3) * 8;
      uint4 v = make_uint4(0u, 0u, 0u, 0u);
      int o = o0 + row;
      if (o < O) v = *(const uint4*)(Wb + (size_t)o * Kpad + k0 + cq);
      *(uint4*)&Ws[row * 40 + cq] = v;
      uint4 xv = *(const uint4*)(Xbb + (size_t)(l0 + row) * Kpad + k0 + cq);
      *(uint4*)&Xs[row * 40 + cq] = xv;
    }
    __syncthreads();
    bf16x8 A[4], Bf[4];
    #pragma unroll
    for (int t = 0; t < 4; ++t) A[t] = *(const bf16x8*)&Ws[(ow_ + t * 16 + m) * 40 + q * 8];
    #pragma unroll
    for (int u = 0; u < 4; ++u) Bf[u] = *(const bf16x8*)&Xs[(lw_ + u * 16 + m) * 40 + q * 8];
    #pragma unroll
    for (int t = 0; t < 4; ++t)
      #pragma unroll
      for (int u = 0; u < 4; ++u)
        acc[t][u] = __builtin_amdgcn_mfma_f32_16x16x32_bf16(A[t], Bf[u], acc[t][u], 0, 0, 0);
    __syncthreads();
  }
  if (act == 3){
    // GLU: reordered rows; pair (even reg r, odd reg r+1); ht row = ro>>1
    #pragma unroll
    for (int t = 0; t < 4; ++t){
      #pragma unroll
      for (int u = 0; u < 4; ++u){
        int l = l0 + lw_ + u * 16 + m;
        #pragma unroll
        for (int r = 0; r < 4; r += 2){
          int ro = o0 + ow_ + t * 16 + q * 4 + r;    // even
          int j = ro >> 1;
          float v1 = acc[t][u][r]   + bias[j];
          float v2 = acc[t][u][r+1] + bias[j + 512];
          out[((size_t)b * 512 + j) * LSEQ + l] = v1 * sigmoid_f(v2);
        }
      }
    }
    return;
  }
  #pragma unroll
  for (int t = 0; t < 4; ++t){
    #pragma unroll
    for (int u = 0; u < 4; ++u){
      int l = l0 + lw_ + u * 16 + m;
      #pragma unroll
      for (int r = 0; r < 4; ++r){
        int o = o0 + ow_ + t * 16 + q * 4 + r;
        if (o >= O) continue;
        size_t oi = ((size_t)b * O + o) * LSEQ + l;
        float v = alpha * acc[t][u][r];
        if (bias) v += bias[o];
        if (res){
          if (sn) v += sn[o] * res[oi] * rinv[b * 2432 + l];
          else v += res[oi];
        }
        if (accf) v += out[oi];
        if (act == 1) v = fmaxf(v, 0.f);
        out[oi] = v * fs;
      }
    }
  }
}

// ---------- conv3: u = gelu(conv1d(hx+noise, cw(512,256,3), cb, pad1)), fp32
__global__ __launch_bounds__(256) void k_conv3(const float* __restrict__ W,
    const float* __restrict__ bias, const float* __restrict__ A,
    const float* __restrict__ Bb, float* __restrict__ U){
  __shared__ float Ws[8][3][68];
  __shared__ float Xs[8][68];
  int l0 = blockIdx.x * 64, o0 = blockIdx.y * 64, b = blockIdx.z;
  int tid = threadIdx.x;
  int tx = tid & 15, ty = tid >> 4;
  float acc[4][4] = {};
  const float* Ab = A + (size_t)b * 256 * LSEQ;
  const float* Nb = Bb + (size_t)b * 256 * LSEQ;
  for (int k0 = 0; k0 < 256; k0 += 8){
    for (int e = tid; e < 1536; e += 256){
      int oo = e / 24, qq = e % 24;
      int kk = qq / 3, t = qq % 3;
      Ws[kk][t][oo] = W[(size_t)(o0 + oo) * 768 + (k0 + kk) * 3 + t];
    }
    for (int e = tid; e < 528; e += 256){
      int kk = e / 66, mm = e % 66;
      int li = l0 - 1 + mm;
      float v = 0.f;
      if (li >= 0 && li < LSEQ){
        size_t ii = (size_t)(k0 + kk) * LSEQ + li;
        v = Ab[ii] + Nb[ii];
      }
      Xs[kk][mm] = v;
    }
    __syncthreads();
    #pragma unroll
    for (int kk = 0; kk < 8; ++kk){
      float x6[6];
      float4 xv = *(const float4*)&Xs[kk][tx * 4];
      x6[0]=xv.x; x6[1]=xv.y; x6[2]=xv.z; x6[3]=xv.w;
      x6[4]=Xs[kk][tx*4+4]; x6[5]=Xs[kk][tx*4+5];
      #pragma unroll
      for (int t = 0; t < 3; ++t){
        float4 wv = *(const float4*)&Ws[kk][t][ty * 4];
        float wa[4]={wv.x,wv.y,wv.z,wv.w};
        #pragma unroll
        for (int i = 0; i < 4; ++i)
          #pragma unroll
          for (int jj = 0; jj < 4; ++jj)
            acc[i][jj] += wa[i] * x6[jj + t];
      }
    }
    __syncthreads();
  }
  #pragma unroll
  for (int i = 0; i < 4; ++i){
    int o = o0 + ty * 4 + i;
    #pragma unroll
    for (int jj = 0; jj < 4; ++jj){
      int l = l0 + tx * 4 + jj;
      U[((size_t)b * 512 + o) * LSEQ + l] = gelu_f(acc[i][jj] + bias[o]);
    }
  }
}

// ---------- s4 causal long conv + D skip, conflict-free fp32 (R2-verified).
#define PHYS(e) ((e) + ((e) >> 3))
__global__ __launch_bounds__(64) void k_s4(const float* __restrict__ kw,
    const float* __restrict__ Dv, const float* __restrict__ u, float* __restrict__ y){
  __shared__ __align__(16) float ksh[256];
  __shared__ __align__(16) float ush[864];
  int l0 = blockIdx.x * 512;
  int hh = blockIdx.y, b = blockIdx.z;
  int t = threadIdx.x;
  const float* kr = kw + (size_t)hh * LSEQ;
  const float* ur = u + ((size_t)b * 512 + hh) * LSEQ;
  float acc[8] = {};
  int lb = t * 8;
  int jmax = l0 + 512; if (jmax > LSEQ) jmax = LSEQ;
  for (int j0 = 0; j0 < jmax; j0 += 256){
    #pragma unroll
    for (int r = 0; r < 4; ++r){
      int e = r * 64 + t;
      int j = j0 + 255 - e;
      ksh[e] = (j < jmax) ? kr[j] : 0.f;
    }
    int base = l0 - j0 - 255;
    #pragma unroll
    for (int r = 0; r < 12; ++r){
      int e = r * 64 + t;
      int ui = base + e;
      ush[PHYS(e)] = (ui >= 0 && ui < LSEQ) ? ur[ui] : 0.f;
    }
    __syncthreads();
    float Wr[8];
    #pragma unroll
    for (int i = 0; i < 8; ++i) Wr[i] = ush[PHYS(lb + i)];
    for (int p = 0; p < 256; p += 16){
      float4 ka = *(const float4*)&ksh[p];
      float4 kb = *(const float4*)&ksh[p + 4];
      float4 kc = *(const float4*)&ksh[p + 8];
      float4 kd = *(const float4*)&ksh[p + 12];
      float N1[8], N2[8];
      #pragma unroll
      for (int i = 0; i < 8; ++i) N1[i] = ush[PHYS(lb + p + 8 + i)];
      float k8a[8] = {ka.x, ka.y, ka.z, ka.w, kb.x, kb.y, kb.z, kb.w};
      #pragma unroll
      for (int mI = 0; mI < 8; ++mI)
        #pragma unroll
        for (int i = 0; i < 8; ++i)
          acc[i] += k8a[mI] * ((i + mI < 8) ? Wr[i + mI] : N1[i + mI - 8]);
      #pragma unroll
      for (int i = 0; i < 8; ++i) N2[i] = ush[PHYS(lb + p + 16 + i)];
      float k8b[8] = {kc.x, kc.y, kc.z, kc.w, kd.x, kd.y, kd.z, kd.w};
      #pragma unroll
      for (int mI = 0; mI < 8; ++mI)
        #pragma unroll
        for (int i = 0; i < 8; ++i)
          acc[i] += k8b[mI] * ((i + mI < 8) ? N1[i + mI] : N2[i + mI - 8]);
      #pragma unroll
      for (int i = 0; i < 8; ++i) Wr[i] = N2[i];
    }
    __syncthreads();
  }
  float dv = Dv[hh];
  #pragma unroll
  for (int i = 0; i < 8; ++i){
    int l = l0 + lb + i;
    if (l < LSEQ) y[((size_t)b * 512 + hh) * LSEQ + l] = acc[i] + dv * ur[l];
  }
}

// ---------- final LayerNorm over last dim (200) with transpose
__global__ __launch_bounds__(256) void k_ln(const float* __restrict__ o2,
    const float* __restrict__ lw, const float* __restrict__ lb2, float* __restrict__ out){
  __shared__ float s1[256], s2[256];
  int row = blockIdx.x;
  int b = row / 2432, l = row % 2432;
  int t = threadIdx.x;
  float v = 0.f;
  if (t < 200) v = o2[((size_t)b * 200 + t) * LSEQ + l];
  s1[t] = v; s2[t] = v * v;
  __syncthreads();
  for (int off = 128; off > 0; off >>= 1){
    if (t < off){ s1[t] += s1[t + off]; s2[t] += s2[t + off]; }
    __syncthreads();
  }
  float m = s1[0] * 0.005f;
  float var = s2[0] * 0.005f - m * m;
  float istd = rsqrtf(var + 1e-5f);
  if (t < 200) out[(size_t)row * 200 + t] = (v - m) * istd * lw[t] + lb2[t];
}

extern "C" void kernel_launch(void* const* d_in, const int* in_sizes, int n_in,
                              void* d_out, int out_size, void* d_ws, size_t ws_size,
                              hipStream_t stream){
  const float* x     = (const float*)d_in[0];
  const float* pe_w  = (const float*)d_in[1];
  const float* pe_b  = (const float*)d_in[2];
  const float* pi0_w = (const float*)d_in[3];
  const float* pi0_b = (const float*)d_in[4];
  const float* gn0_w = (const float*)d_in[5];
  const float* gn0_b = (const float*)d_in[6];
  const float* pi1_w = (const float*)d_in[7];
  const float* pi1_b = (const float*)d_in[8];
  const float* gn1_w = (const float*)d_in[9];
  const float* gn1_b = (const float*)d_in[10];
  const float* pi2_w = (const float*)d_in[11];
  const float* pi2_b = (const float*)d_in[12];
  const float* gn2_w = (const float*)d_in[13];
  const float* gn2_b = (const float*)d_in[14];
  const float* spec_w= (const float*)d_in[15];
  const float* spec_b= (const float*)d_in[16];
  const float* ic_w  = (const float*)d_in[17];
  const float* ic_b  = (const float*)d_in[18];
  const float* blk_sn= (const float*)d_in[19];
  const float* blk_cw= (const float*)d_in[20];
  const float* blk_cb= (const float*)d_in[21];
  const float* blk_k = (const float*)d_in[22];
  const float* blk_D = (const float*)d_in[23];
  const float* blk_ow= (const float*)d_in[24];
  const float* blk_ob= (const float*)d_in[25];
  const float* blk_Wv= (const float*)d_in[26];
  const float* blk_bv= (const float*)d_in[27];
  const float* blk_Wo= (const float*)d_in[28];
  const float* blk_bo= (const float*)d_in[29];
  const float* blk_rw= (const float*)d_in[30];
  const float* blk_rb= (const float*)d_in[31];
  const float* blk_sw= (const float*)d_in[32];
  const float* blk_sb= (const float*)d_in[33];
  const float* fc_w  = (const float*)d_in[34];
  const float* fc_b  = (const float*)d_in[35];
  const float* zc_w  = (const float*)d_in[36];
  const float* zc_b  = (const float*)d_in[37];
  const float* ln_w  = (const float*)d_in[38];
  const float* ln_b  = (const float*)d_in[39];

  float* Wsp = (float*)d_ws;
  const size_t NLL = (size_t)8 * 256 * 2432;    // 4,980,736 floats
  // layout (float units): total 63,152,208 floats = 252.6 MB (< proven 259 MB)
  float* noise = Wsp;                 // [0,1)
  float* hxb   = Wsp + NLL;           // [1,2)
  float* skb   = Wsp + 2 * NLL;       // [2,3)
  float* ub    = Wsp + 3 * NLL;       // [3,5)  u / v / a / fc-out
  float* ysb   = Wsp + 5 * NLL;       // [5,7)  s4-out per s / ht / zc-out
  float* htb   = ysb;
  unsigned short* actT = (unsigned short*)(Wsp + 7 * NLL);   // [7,11) bf16 [b][l][2048]
  unsigned short* wB = (unsigned short*)(Wsp + 11 * NLL);
  unsigned short* owB = wB;                    // 6*1024*2048 = 12,582,912
  unsigned short* WvB = wB + 12582912;         // 1,572,864
  unsigned short* WoB = wB + 14155776;         // 1,572,864
  unsigned short* rwB = wB + 15728640;         // 393,216
  unsigned short* swB = wB + 16121856;         // 393,216
  unsigned short* icB = wB + 16515072;         // 57,344
  unsigned short* fcB = wB + 16572416;         // 65,536
  unsigned short* zcB = wB + 16637952;         // 51,200 -> end 16,689,152 ushorts
  float* rinv   = Wsp + 11 * NLL + 8344576;    // 19,456 floats
  float* gnstats= rinv + 19456;                // 80 floats

  // front-end aliases (regions dead at that point)
  float* p0 = ub;
  float* p1 = ysb;
  float* p2 = ub;
  float* pe = Wsp + 7 * NLL;          // actT region (floats), dead before first castT use
  float* spec = Wsp + 8 * NLL;
  float* peT = skb;                   // skb garbage OK (first sw gemm accf=0)
  float* hb = hxb;                    // overwritten later by memcpy noise->hxb

  const float SQ05 = 0.70710678118654752440f;
  const float SQ16 = 0.40824829046386301637f;

  // ---- weight casts (bf16) ----
  k_wcast_glu<<<49152,256,0,stream>>>(blk_ow, owB);
  k_wcast<<<(3072*512+255)/256,256,0,stream>>>(blk_Wv, WvB, 3072, 512, 512);
  k_wcast<<<(3072*512+255)/256,256,0,stream>>>(blk_Wo, WoB, 3072, 512, 512);
  k_wcast<<<(1536*256+255)/256,256,0,stream>>>(blk_rw, rwB, 1536, 256, 256);
  k_wcast<<<(1536*256+255)/256,256,0,stream>>>(blk_sw, swB, 1536, 256, 256);
  k_wcast<<<(256*224+255)/256,256,0,stream>>>(ic_w, icB, 256, 200, 224);
  k_wcast<<<(256*256+255)/256,256,0,stream>>>(fc_w, fcB, 256, 256, 256);
  k_wcast<<<(200*256+255)/256,256,0,stream>>>(zc_w, zcB, 200, 256, 256);

  // ---- PatchEmbedding ----
  k_pi0<<<dim3(76,25,8), 256, 0, stream>>>(x, pi0_w, pi0_b, p0);
  k_gn_reduce<<<40,256,0,stream>>>(p0, gnstats);
  k_gn_apply<<<15200,256,0,stream>>>(p0, gnstats, gn0_w, gn0_b);
  k_pconv3<<<dim3(76,25,8),256,0,stream>>>(p0, pi1_w, pi1_b, p1);
  k_gn_reduce<<<40,256,0,stream>>>(p1, gnstats);
  k_gn_apply<<<15200,256,0,stream>>>(p1, gnstats, gn1_w, gn1_b);
  k_pconv3<<<dim3(76,25,8),256,0,stream>>>(p1, pi2_w, pi2_b, p2);
  k_gn_reduce<<<40,256,0,stream>>>(p2, gnstats);
  k_gn_apply<<<15200,256,0,stream>>>(p2, gnstats, gn2_w, gn2_b);
  k_pe_build<<<15200,256,0,stream>>>(p2, pe);
  k_spec<<<19456,256,0,stream>>>(x, spec);
  k_spec_mm<<<19456,256,0,stream>>>(spec, spec_w, spec_b, pe);
  k_trp<<<dim3(76,7,8),256,0,stream>>>(pe, peT);
  k_hbuild2<<<dim3(19,200,8),128,0,stream>>>(peT, pe_w, pe_b, hb);
  k_castT<<<dim3(76,7,8),256,0,stream>>>(hb, actT, 200, 224, 0);
  k_bgemm<<<dim3(19,2,8),256,0,stream>>>(icB, actT, ic_b, nullptr, nullptr, nullptr,
                                         noise, 256, 224, 1.f, 1.f, 1, 0);
  hipMemcpyAsync(hxb, noise, NLL * sizeof(float), hipMemcpyDeviceToDevice, stream);

  // ---- residual blocks ----
  for (int i = 0; i < 6; ++i){
    const float* sn = blk_sn + i * 256;
    const float* cw = blk_cw + (size_t)i * 512 * 768;
    const float* cb = blk_cb + i * 512;
    const float* ob = blk_ob + i * 1024;
    const float* bv = blk_bv + i * 512;
    const float* bo = blk_bo + i * 512;
    const float* rb = blk_rb + i * 256;
    const float* sb = blk_sb + i * 256;

    k_rmsr<<<76,256,0,stream>>>(hxb, rinv);
    k_conv3<<<dim3(38,8,8),256,0,stream>>>(cw, cb, hxb, noise, ub);
    for (int s = 0; s < 4; ++s){
      const float* kw = blk_k + ((size_t)i * 4 + s) * 512 * 2432;
      const float* Dv = blk_D + ((size_t)i * 4 + s) * 512;
      k_s4<<<dim3(5,512,8),64,0,stream>>>(kw, Dv, ub, ysb);
      k_castT<<<dim3(76,16,8),256,0,stream>>>(ysb, actT, 512, 2048, s * 512);
    }
    // fused ow-GEMM + GLU -> ht (512 ch)
    k_bgemm<<<dim3(19,8,8),256,0,stream>>>(owB + (size_t)i*1024*2048, actT, ob,
                                           nullptr, nullptr, nullptr, htb,
                                           1024, 2048, 1.f, 1.f, 3, 0);
    k_castT<<<dim3(76,16,8),256,0,stream>>>(htb, actT, 512, 512, 0);
    k_bgemm<<<dim3(19,4,8),256,0,stream>>>(WvB + (size_t)i*512*512, actT, bv,
                                           nullptr, nullptr, nullptr, ub,
                                           512, 512, 1.f, 1.f, 0, 0);
    k_castT<<<dim3(76,16,8),256,0,stream>>>(ub, actT, 512, 512, 0);
    k_bgemm<<<dim3(19,4,8),256,0,stream>>>(WoB + (size_t)i*512*512, actT, bo,
                                           nullptr, nullptr, nullptr, ub,
                                           512, 512, 1.f, 1.f, 0, 0);
    k_gateT<<<dim3(76,8,8),256,0,stream>>>(htb, ub, actT);
    // rw-GEMM with fused RMS residual: hx = (sn*hx*rinv + rw@out + rb)*sqrt(0.5)
    k_bgemm<<<dim3(19,2,8),256,0,stream>>>(rwB + (size_t)i*256*256, actT, rb,
                                           hxb, sn, rinv, hxb,
                                           256, 256, 1.f, SQ05, 0, 0);
    k_bgemm<<<dim3(19,2,8),256,0,stream>>>(swB + (size_t)i*256*256, actT, sb,
                                           nullptr, nullptr, nullptr, skb,
                                           256, 256, 1.f, 1.f, 0, i==0?0:1);
  }

  // ---- tail ----
  k_castT<<<dim3(76,8,8),256,0,stream>>>(skb, actT, 256, 256, 0);
  k_bgemm<<<dim3(19,2,8),256,0,stream>>>(fcB, actT, fc_b, nullptr, nullptr, nullptr,
                                         ub, 256, 256, SQ16, 1.f, 1, 0);
  k_castT<<<dim3(76,8,8),256,0,stream>>>(ub, actT, 256, 256, 0);
  k_bgemm<<<dim3(19,2,8),256,0,stream>>>(zcB, actT, zc_b, nullptr, nullptr, nullptr,
                                         ysb, 200, 256, 1.f, 1.f, 0, 0);
  k_ln<<<19456,256,0,stream>>>(ysb, ln_w, ln_b, (float*)d_out);
}